// Round 11
// baseline (364.864 us; speedup 1.0000x reference)
//
#include <hip/hip_runtime.h>
#include <hip/hip_bf16.h>

// Sparse 3^3 conv x2 + LayerNorm + ReLU + residual. N=400000, C=32, K=27.
// Contract: ALL float inputs are FLOAT32, output f32, nbr int32.
// Workspace: h (bf16, 25.6MB) at d_ws+0; xb (bf16 copy of x) at +25.6MB.
//
// Round-11 (post-mortem r10: index-prefetch deepening 2->6 changed nothing
// -- passes 84.8us, clean counters -- pre-committed conclusion: the exposed
// chain is the DATA gather, issued only ~1 consume (~150cy) before use vs
// ~200-900cy L2/HBM scatter latency. Fix: depth-2 data pipeline -- four
// named buffers gA..gD (kk mod 4), gather lead = 2 full iterations
// (~400-600cy). idx rotation widened to mod 8 so index lead stays 2 iters.
// Reg audit: r10 = 60 arch + 32 acc AGPR; +32 buf +2 idx -> ~94+32 = 126
// <= 128 cap of (512,4). Everything else byte-identical to r10.
// Pre-commit: VGPR<=64 AND WRITE>55MB => spill => revert to r10 body;
// passes unchanged w/ clean counters => TLP covers latency, next lever is
// per-iteration instruction count, not depth.)

#define NV 400000
#define NT 782          // ceil(NV / 512) blocks; 8 waves x 64 voxels each

typedef __bf16 bf16x8 __attribute__((ext_vector_type(8)));
typedef float  f32x4  __attribute__((ext_vector_type(4)));

union ABu { bf16x8 v; int4 i4; unsigned short us[8]; };

__device__ __forceinline__ unsigned short rb_f2bf(float f) {
    unsigned int u = __float_as_uint(f);
    return (unsigned short)((u + 0x7fffu + ((u >> 16) & 1u)) >> 16);
}

// k index for the 26 non-center offsets (skips k=13, the identity offset)
#define KIDX(kk) ((kk) + ((kk) >= 13 ? 1 : 0))

#define MFMA_BF16 __builtin_amdgcn_mfma_f32_16x16x32_bf16

// x (f32) -> bf16, 8 elems/thread. Exact grid: NV*32/8/512 = 3125 blocks.
__global__ __launch_bounds__(512) void xcvt_kernel(const float* __restrict__ xf,
                                                   unsigned short* __restrict__ xb)
{
    size_t i = ((size_t)blockIdx.x * 512 + threadIdx.x) * 8;
    float4 p0 = *(const float4*)(xf + i);
    float4 p1 = *(const float4*)(xf + i + 4);
    ABu a;
    a.us[0] = rb_f2bf(p0.x); a.us[1] = rb_f2bf(p0.y);
    a.us[2] = rb_f2bf(p0.z); a.us[3] = rb_f2bf(p0.w);
    a.us[4] = rb_f2bf(p1.x); a.us[5] = rb_f2bf(p1.y);
    a.us[6] = rb_f2bf(p1.z); a.us[7] = rb_f2bf(p1.w);
    *(int4*)(xb + i) = a.i4;
}

// Gather the 4 tile-slots for one offset from a wave-wide index register.
// jall lane l holds nbr index of voxel i0+l; tile t row n needs lane t*16+n.
#define GATHER4(gbuf, jall)                                                   \
    do {                                                                      \
        _Pragma("unroll")                                                     \
        for (int _t = 0; _t < 4; ++_t) {                                      \
            int _j = __shfl((jall), _t * 16 + n);                             \
            gbuf[_t] = make_int4(0, 0, 0, 0);                                 \
            if (_j >= 0)                                                      \
                gbuf[_t] = *(const int4*)(gsrc + ((size_t)_j << 5) + qo);     \
        }                                                                     \
    } while (0)

// Consume one offset's gather buffer: 2 LDS B-frag reads + 8 MFMAs.
#define CONSUME(kk, gbuf)                                                     \
    do {                                                                      \
        ABu _b0, _b1;                                                         \
        _b0.i4 = *(const int4*)(Bp + (kk) * 1024 + lane * 8);                 \
        _b1.i4 = *(const int4*)(Bp + (kk) * 1024 + 512 + lane * 8);           \
        _Pragma("unroll")                                                     \
        for (int _t = 0; _t < 4; ++_t) {                                      \
            ABu _a; _a.i4 = gbuf[_t];                                         \
            acc[_t][0] = MFMA_BF16(_a.v, _b0.v, acc[_t][0], 0, 0, 0);         \
            acc[_t][1] = MFMA_BF16(_a.v, _b1.v, acc[_t][1], 0, 0, 0);         \
        }                                                                     \
    } while (0)

#define NBLOAD(kk)                                                            \
    (okv ? __builtin_nontemporal_load(nbr + (size_t)KIDX(kk) * NV + v64) : -1)

// WRITE_OUT=false: h(bf16) = relu(LN(conv1(xb)))       gsrc = xb
// WRITE_OUT=true : out(f32) = relu(LN(conv2(h)) + x)   gsrc = h
template <bool WRITE_OUT>
__global__ __launch_bounds__(512, 4) void pass_kernel(
    const float* __restrict__ xf,     // x [NV,32] f32 (residual, pass 2)
    const int*   __restrict__ nbr,    // [27,NV]
    const float* __restrict__ Wf,     // [27,32,32] f32
    const float* __restrict__ gf,     // [32]
    const float* __restrict__ bfv,    // [32]
    float*       __restrict__ outf,   // [NV,32] f32
    unsigned short* __restrict__ hbuf,// [NV,32] bf16 (pass-1 dst)
    const unsigned short* __restrict__ gsrc)  // bf16 gather source
{
    // Bp[kk*1024 + f*512 + lane*8 + j] = W[k][ci=(lane>>4)*8+j][co=(lane&15)+16f]
    __shared__ __align__(16) unsigned short Bp[26 * 1024];

    const int  lane = threadIdx.x & 63;
    const int  wv   = threadIdx.x >> 6;
    const int  q    = lane >> 4, n = lane & 15;
    const int  i0   = blockIdx.x * 512 + wv * 64;
    const int  v64  = i0 + lane;
    const bool okv  = v64 < NV;
    const int  qo   = q * 8;          // bf16-element offset within row

    // ---- index prefetch: 8 offsets in flight (mod-8 rotation), issued FIRST
    // so the HBM latency hides under the LDS fill + prologue. ----
    int idx[8];
    #pragma unroll
    for (int kk = 0; kk < 8; ++kk) idx[kk] = NBLOAD(kk);

    // center self-rows (identity map k=13, coalesced) -- issued early too
    int4 cgb[4];
    #pragma unroll
    for (int t = 0; t < 4; ++t) {
        int vt = i0 + t * 16 + n;
        cgb[t] = make_int4(0, 0, 0, 0);
        if (vt < NV) cgb[t] = *(const int4*)(gsrc + ((size_t)vt << 5) + qo);
    }

    // center-offset B fragments from global f32 weights (independent of LDS)
    ABu cb0, cb1;
    #pragma unroll
    for (int j = 0; j < 8; ++j) {
        int ci = (q << 3) + j;
        cb0.us[j] = rb_f2bf(Wf[13 * 1024 + ci * 32 + n]);
        cb1.us[j] = rb_f2bf(Wf[13 * 1024 + ci * 32 + n + 16]);
    }

    // LDS fill: 26 non-center offsets (long; covers the loads above)
    for (int e = threadIdx.x; e < 26 * 1024; e += 512) {
        int kk = e >> 10;
        int k  = KIDX(kk);
        int r  = e & 1023;
        int f  = r >> 9;
        int ll = (r >> 3) & 63;
        int j  = r & 7;
        int ci = ((ll >> 4) << 3) + j;
        int co = (ll & 15) + (f << 4);
        Bp[e] = rb_f2bf(Wf[k * 1024 + ci * 32 + co]);
    }
    __syncthreads();

    f32x4 acc[4][2];
    #pragma unroll
    for (int t = 0; t < 4; ++t) {
        acc[t][0] = (f32x4){0.f, 0.f, 0.f, 0.f};
        acc[t][1] = (f32x4){0.f, 0.f, 0.f, 0.f};
    }

    // ---- depth-2 prologue: fill gA,gB (kk=0,1); retire center (frees
    // cgb+cb regs before gC,gD go live); fill gC,gD (kk=2,3). ----
    int4 gA[4], gB[4], gC[4], gD[4];
    GATHER4(gA, idx[0]);               // kk=0
    GATHER4(gB, idx[1]);               // kk=1

    #pragma unroll
    for (int t = 0; t < 4; ++t) {
        ABu a; a.i4 = cgb[t];
        acc[t][0] = MFMA_BF16(a.v, cb0.v, acc[t][0], 0, 0, 0);
        acc[t][1] = MFMA_BF16(a.v, cb1.v, acc[t][1], 0, 0, 0);
    }

    GATHER4(gC, idx[2]);               // kk=2
    GATHER4(gD, idx[3]);               // kk=3

    // ---- main pipeline: 13 pairs, fully unrolled. Buffer for kk = kk mod 4
    // (p even: gA,gB; p odd: gC,gD). Gather for kk issued at the consume of
    // kk-4 -> lead = 2 full iterations (~400-600cy). idx slot audit (mod 8):
    // iter p writes slots (2p)%8,(2p+1)%8 for kk=2p+8; gathers read slots
    // (2p+4)%8,(2p+5)%8 (kk=2p+4, written 2 iters ago) -- disjoint. ----
    #pragma unroll
    for (int p = 0; p < 13; ++p) {
        if (2 * p + 8 < 26) idx[(2 * p + 8) % 8] = NBLOAD(2 * p + 8);
        if (2 * p + 9 < 26) idx[(2 * p + 9) % 8] = NBLOAD(2 * p + 9);

        if ((p & 1) == 0) {
            CONSUME(2 * p, gA);
            if (2 * p + 4 < 26) GATHER4(gA, idx[(2 * p + 4) % 8]);
            CONSUME(2 * p + 1, gB);
            if (2 * p + 5 < 26) GATHER4(gB, idx[(2 * p + 5) % 8]);
        } else {
            CONSUME(2 * p, gC);
            if (2 * p + 4 < 26) GATHER4(gC, idx[(2 * p + 4) % 8]);
            CONSUME(2 * p + 1, gD);
            if (2 * p + 5 < 26) GATHER4(gD, idx[(2 * p + 5) % 8]);
        }
    }

    // epilogue. C/D layout: cout = lane&15 (+16 frag1), voxel row = q*4+r.
    const float gv0 = gf[n],  gv1 = gf[n + 16];
    const float bv0 = bfv[n], bv1 = bfv[n + 16];
    #pragma unroll
    for (int t = 0; t < 4; ++t) {
        #pragma unroll
        for (int r = 0; r < 4; ++r) {
            float x0 = acc[t][0][r], x1 = acc[t][1][r];
            float s  = x0 + x1;
            float ss = x0 * x0 + x1 * x1;
            #pragma unroll
            for (int mm = 1; mm <= 8; mm <<= 1) {   // LN reduce, 16-lane group
                s  += __shfl_xor(s, mm);
                ss += __shfl_xor(ss, mm);
            }
            float mu  = s * (1.f / 32.f);
            float var = ss * (1.f / 32.f) - mu * mu;
            float rs  = rsqrtf(var + 1e-6f);
            int vv = i0 + t * 16 + q * 4 + r;
            if (vv < NV) {
                float y0 = (x0 - mu) * rs * gv0 + bv0;
                float y1 = (x1 - mu) * rs * gv1 + bv1;
                if constexpr (WRITE_OUT) {
                    y0 += xf[(size_t)vv * 32 + n];
                    y1 += xf[(size_t)vv * 32 + n + 16];
                    outf[(size_t)vv * 32 + n]      = fmaxf(y0, 0.f);
                    outf[(size_t)vv * 32 + n + 16] = fmaxf(y1, 0.f);
                } else {
                    hbuf[(size_t)vv * 32 + n]      = rb_f2bf(fmaxf(y0, 0.f));
                    hbuf[(size_t)vv * 32 + n + 16] = rb_f2bf(fmaxf(y1, 0.f));
                }
            }
        }
    }
}

// Fallback pass-1 for tiny workspace (no xb room): f32 gathers from x,
// round-0-proven serial structure. Only used when ws_size < 51.2MB.
__global__ __launch_bounds__(512, 4) void pass1_f32_kernel(
    const float* __restrict__ xf, const int* __restrict__ nbr,
    const float* __restrict__ Wf, const float* __restrict__ gf,
    const float* __restrict__ bfv, unsigned short* __restrict__ hbuf)
{
    __shared__ __align__(16) unsigned short Bp[27 * 1024];
    for (int e = threadIdx.x; e < 27 * 1024; e += 512) {
        int k = e >> 10, r = e & 1023, f = r >> 9;
        int ll = (r >> 3) & 63, j = r & 7;
        int ci = ((ll >> 4) << 3) + j, co = (ll & 15) + (f << 4);
        Bp[e] = rb_f2bf(Wf[k * 1024 + ci * 32 + co]);
    }
    __syncthreads();
    const int lane = threadIdx.x & 63, wv = threadIdx.x >> 6;
    const int q = lane >> 4, n = lane & 15;
    const int i0 = blockIdx.x * 512 + wv * 64;
    f32x4 acc[4][2];
    #pragma unroll
    for (int t = 0; t < 4; ++t) { acc[t][0] = (f32x4){0,0,0,0}; acc[t][1] = (f32x4){0,0,0,0}; }
    for (int k = 0; k < 27; ++k) {
        ABu b0, b1;
        b0.i4 = *(const int4*)(Bp + k * 1024 + lane * 8);
        b1.i4 = *(const int4*)(Bp + k * 1024 + 512 + lane * 8);
        const int* nb = nbr + (size_t)k * NV;
        #pragma unroll
        for (int t = 0; t < 4; ++t) {
            int v = i0 + t * 16 + n;
            int jn = (v < NV) ? nb[v] : -1;
            if (__ballot(jn >= 0) == 0ull) continue;
            ABu a; a.i4 = make_int4(0, 0, 0, 0);
            if (jn >= 0) {
                const float* src = xf + (size_t)jn * 32 + q * 8;
                float4 p0 = *(const float4*)(src);
                float4 p1 = *(const float4*)(src + 4);
                a.us[0] = rb_f2bf(p0.x); a.us[1] = rb_f2bf(p0.y);
                a.us[2] = rb_f2bf(p0.z); a.us[3] = rb_f2bf(p0.w);
                a.us[4] = rb_f2bf(p1.x); a.us[5] = rb_f2bf(p1.y);
                a.us[6] = rb_f2bf(p1.z); a.us[7] = rb_f2bf(p1.w);
            }
            acc[t][0] = MFMA_BF16(a.v, b0.v, acc[t][0], 0, 0, 0);
            acc[t][1] = MFMA_BF16(a.v, b1.v, acc[t][1], 0, 0, 0);
        }
    }
    const float gv0 = gf[n], gv1 = gf[n + 16];
    const float bv0 = bfv[n], bv1 = bfv[n + 16];
    #pragma unroll
    for (int t = 0; t < 4; ++t) {
        #pragma unroll
        for (int r = 0; r < 4; ++r) {
            float x0 = acc[t][0][r], x1 = acc[t][1][r];
            float s = x0 + x1, ss = x0 * x0 + x1 * x1;
            #pragma unroll
            for (int mm = 1; mm <= 8; mm <<= 1) { s += __shfl_xor(s, mm); ss += __shfl_xor(ss, mm); }
            float mu = s * (1.f / 32.f);
            float var = ss * (1.f / 32.f) - mu * mu;
            float rs = rsqrtf(var + 1e-6f);
            int vv = i0 + t * 16 + q * 4 + r;
            if (vv < NV) {
                float y0 = (x0 - mu) * rs * gv0 + bv0;
                float y1 = (x1 - mu) * rs * gv1 + bv1;
                hbuf[(size_t)vv * 32 + n]      = rb_f2bf(fmaxf(y0, 0.f));
                hbuf[(size_t)vv * 32 + n + 16] = rb_f2bf(fmaxf(y1, 0.f));
            }
        }
    }
}

extern "C" void kernel_launch(void* const* d_in, const int* in_sizes, int n_in,
                              void* d_out, int out_size, void* d_ws, size_t ws_size,
                              hipStream_t stream)
{
    // setup_inputs() dict order: x, nbr, W1, g1, b1, W2, g2, b2 — all f32 except nbr
    const float* x   = (const float*)d_in[0];
    const int*   nbr = (const int*)d_in[1];
    const float* W1  = (const float*)d_in[2];
    const float* g1  = (const float*)d_in[3];
    const float* b1  = (const float*)d_in[4];
    const float* W2  = (const float*)d_in[5];
    const float* g2  = (const float*)d_in[6];
    const float* b2  = (const float*)d_in[7];
    float* out = (float*)d_out;

    unsigned short* h  = (unsigned short*)d_ws;              // 25.6 MB
    unsigned short* xb = h + (size_t)NV * 32;                // +25.6 MB
    const bool have_xb = ws_size >= (size_t)NV * 32 * 2 * 2; // 51.2 MB needed

    if (have_xb) {
        // pass 0: xb = bf16(x)
        xcvt_kernel<<<3125, 512, 0, stream>>>(x, xb);
        // pass 1: h = relu(LN(conv1(xb)))
        pass_kernel<false><<<NT, 512, 0, stream>>>(x, nbr, W1, g1, b1, out, h, xb);
    } else {
        pass1_f32_kernel<<<NT, 512, 0, stream>>>(x, nbr, W1, g1, b1, h);
    }
    // pass 2: out = relu(LN(conv2(h)) + x)
    pass_kernel<true><<<NT, 512, 0, stream>>>(x, nbr, W2, g2, b2, out, h, h);

    (void)in_sizes; (void)n_in; (void)out_size;
}